// Round 1
// baseline (449.072 us; speedup 1.0000x reference)
//
#include <hip/hip_runtime.h>
#include <stdint.h>

#define EFFECT_DIM 758
#define ADD_DIM 10
#define EMBED_DIM 768
#define NCOLS 95000
#define NSYN 8
#define NROWS 1024

typedef __attribute__((ext_vector_type(8))) __bf16 bf16x8;
typedef __attribute__((ext_vector_type(16))) float f32x16;
typedef __attribute__((ext_vector_type(4))) uint32_t u32x4;

static __device__ __forceinline__ uint32_t f2bf(float x) {
  uint32_t u = __float_as_uint(x);
  uint32_t r = (u + 0x7fffu + ((u >> 16) & 1u)) >> 16;
  return r & 0xffffu;
}
static __device__ __forceinline__ uint32_t pack2(float a, float b) {
  return f2bf(a) | (f2bf(b) << 16);
}

// ---------------------------------------------------------------------------
// Kernel 1: VirtualEmbedding -> bf16 A tiles in ws.
// ws layout: tile(mt, ks) at (mt*12+ks)*16384 bytes, [128 rows][64 cols] bf16,
// stored swizzled: byte(r, c2) = r*128 + (c2 ^ ((r&7)<<4)).
// ---------------------------------------------------------------------------
__global__ __launch_bounds__(256) void emb_kernel(
    const int* __restrict__ ids, const float* __restrict__ W_emb,
    const float* __restrict__ padding, const int* __restrict__ syn_table,
    const int* __restrict__ syn_mask, char* __restrict__ ws)
{
  const int l = blockIdx.x;
  const int t = threadIdx.x;
  const int id = ids[l];
  int sid[NSYN];
  int msk[NSYN];
#pragma unroll
  for (int k = 0; k < NSYN; ++k) {
    sid[k] = syn_table[id * NSYN + k];
    msk[k] = syn_mask[id * NSYN + k];
  }

  // f64 partial sums: p[0]=base row, p[1..8]=synonym rows
  double p[9] = {0, 0, 0, 0, 0, 0, 0, 0, 0};
  for (int d = t; d < EFFECT_DIM; d += 256) {
    p[0] += (double)W_emb[(size_t)id * EFFECT_DIM + d];
#pragma unroll
    for (int k = 0; k < NSYN; ++k)
      p[k + 1] += (double)W_emb[(size_t)sid[k] * EFFECT_DIM + d];
  }

  __shared__ double s_red[9][4];
  const int w = t >> 6;
#pragma unroll
  for (int k = 0; k < 9; ++k) {
    double v = p[k];
#pragma unroll
    for (int off = 32; off > 0; off >>= 1) v += __shfl_down(v, off, 64);
    if ((t & 63) == 0) s_red[k][w] = v;
  }
  __syncthreads();

  const double isum = s_red[0][0] + s_red[0][1] + s_red[0][2] + s_red[0][3];
  float coef[NSYN];
#pragma unroll
  for (int k = 0; k < NSYN; ++k) {
    double ss = s_red[k + 1][0] + s_red[k + 1][1] + s_red[k + 1][2] + s_red[k + 1][3];
    coef[k] = msk[k] ? (float)(isum / ss) : 0.0f;
  }

  const int mt = l >> 7;
  const int r  = l & 127;
  const int sw = (r & 7) << 4;
  char* wbase = ws + (size_t)mt * (12 * 16384);

  // 384 bf16-pairs cover the 768 columns of this row
  for (int j = t; j < 384; j += 256) {
    const int d0 = 2 * j;
    float v0, v1;
    if (d0 < EFFECT_DIM) {
      const float* bp = W_emb + (size_t)id * EFFECT_DIM + d0;
      v0 = bp[0];
      v1 = bp[1];
#pragma unroll
      for (int k = 0; k < NSYN; ++k) {
        const float* sp = W_emb + (size_t)sid[k] * EFFECT_DIM + d0;
        v0 = fmaf(coef[k], sp[0], v0);
        v1 = fmaf(coef[k], sp[1], v1);
      }
    } else {
      v0 = padding[l * ADD_DIM + (d0 - EFFECT_DIM)];
      v1 = padding[l * ADD_DIM + (d0 + 1 - EFFECT_DIM)];
    }
    const int ks = j >> 5;   // which 64-col k-tile
    const int jl = j & 31;   // 4-byte group inside the tile row
    *(uint32_t*)(wbase + ks * 16384 + r * 128 + ((jl * 4) ^ sw)) = pack2(v0, v1);
  }
}

// ---------------------------------------------------------------------------
// Kernel 2: out[1024 x 95000] f32 = A(bf16, ws) x W_rev(f32 -> bf16 on the fly)
// 128x128 block tile, BK=64, 4 waves in 2x2, wave tile 64x64 via
// mfma_f32_32x32x16_bf16 (M_rep=N_rep=2, 4 k-chunks of 16).
// ---------------------------------------------------------------------------
__global__ __launch_bounds__(256, 2) void gemm_kernel(
    const float* __restrict__ Wrev, const char* __restrict__ Abuf,
    float* __restrict__ out)
{
  __shared__ char lds[32768];  // A: [0,16384), B: [16384,32768)
  const int t  = threadIdx.x;
  const int l  = t & 63;
  const int w  = t >> 6;
  const int wm = w >> 1;
  const int wn = w & 1;
  const int lr = l & 31;
  const int lh = l >> 5;  // lane half -> k offset 0/8
  const int mt = blockIdx.x;
  const int n0 = blockIdx.y * 128;

  f32x16 acc[2][2] = {};

  const char* asrc = Abuf + (size_t)mt * (12 * 16384);
  const int nl = t & 127;             // B-stage: this thread's n within tile
  const int kc_base = t >> 7;         // 0 or 1
  const int gn = n0 + nl;
  const int bswz = (nl & 7) << 4;

  for (int ks = 0; ks < 12; ++ks) {
    // ---- stage A: 16KB linear copy ws -> LDS (pre-swizzled in ws) ----
    {
      const char* s = asrc + ks * 16384 + w * 1024 + l * 16;
      char* d = lds + w * 1024;  // wave-uniform base; HW adds lane*16
#pragma unroll
      for (int i = 0; i < 4; ++i) {
        __builtin_amdgcn_global_load_lds(
            (const __attribute__((address_space(1))) uint32_t*)(s + i * 4096),
            (__attribute__((address_space(3))) uint32_t*)(d + i * 4096),
            16, 0, 0);
      }
    }
    // ---- stage B: f32 [64k x 128n] -> bf16 LDS [n][k] swizzled ----
#pragma unroll
    for (int task = 0; task < 4; ++task) {
      const int kc = kc_base + task * 2;  // 0..7, 8-k chunk
      float v[8];
      const float* p = Wrev + (size_t)(ks * 64 + kc * 8) * NCOLS + gn;
#pragma unroll
      for (int j = 0; j < 8; ++j)
        v[j] = (gn < NCOLS) ? p[(size_t)j * NCOLS] : 0.0f;
      u32x4 u;
#pragma unroll
      for (int j = 0; j < 4; ++j)
        u[j] = pack2(v[2 * j], v[2 * j + 1]);
      *(u32x4*)(lds + 16384 + nl * 128 + ((kc * 16) ^ bswz)) = u;
    }
    __syncthreads();

    // ---- fragments ----
    bf16x8 af[2][4], bg[2][4];
#pragma unroll
    for (int mr = 0; mr < 2; ++mr) {
      const int rr = wm * 64 + mr * 32 + lr;
      const int swz = (rr & 7) << 4;
#pragma unroll
      for (int kk = 0; kk < 4; ++kk) {
        const int c2 = kk * 32 + lh * 16;
        af[mr][kk] = *(const bf16x8*)(lds + rr * 128 + (c2 ^ swz));
      }
    }
#pragma unroll
    for (int nr = 0; nr < 2; ++nr) {
      const int rr = wn * 64 + nr * 32 + lr;
      const int swz = (rr & 7) << 4;
#pragma unroll
      for (int kk = 0; kk < 4; ++kk) {
        const int c2 = kk * 32 + lh * 16;
        bg[nr][kk] = *(const bf16x8*)(lds + 16384 + rr * 128 + (c2 ^ swz));
      }
    }
    // ---- MFMA ----
#pragma unroll
    for (int kk = 0; kk < 4; ++kk)
#pragma unroll
      for (int mr = 0; mr < 2; ++mr)
#pragma unroll
        for (int nr = 0; nr < 2; ++nr)
          acc[mr][nr] = __builtin_amdgcn_mfma_f32_32x32x16_bf16(
              af[mr][kk], bg[nr][kk], acc[mr][nr], 0, 0, 0);
    __syncthreads();
  }

  // ---- epilogue: C layout col=lane&31, row=(reg&3)+8*(reg>>2)+4*(lane>>5) ----
#pragma unroll
  for (int mr = 0; mr < 2; ++mr)
#pragma unroll
    for (int nr = 0; nr < 2; ++nr) {
      const int gc = n0 + wn * 64 + nr * 32 + lr;
      if (gc < NCOLS) {
#pragma unroll
        for (int reg = 0; reg < 16; ++reg) {
          const int row = (reg & 3) + 8 * (reg >> 2) + 4 * lh;
          const int gr = mt * 128 + wm * 64 + mr * 32 + row;
          out[(size_t)gr * NCOLS + gc] = acc[mr][nr][reg];
        }
      }
    }
}

extern "C" void kernel_launch(void* const* d_in, const int* in_sizes, int n_in,
                              void* d_out, int out_size, void* d_ws, size_t ws_size,
                              hipStream_t stream) {
  const int*   ids       = (const int*)d_in[0];
  const float* W_emb     = (const float*)d_in[1];
  const float* W_rev     = (const float*)d_in[2];
  const float* padding   = (const float*)d_in[3];
  const int*   syn_table = (const int*)d_in[4];
  const int*   syn_mask  = (const int*)d_in[5];
  float* out = (float*)d_out;
  char*  ws  = (char*)d_ws;

  hipLaunchKernelGGL(emb_kernel, dim3(NROWS), dim3(256), 0, stream,
                     ids, W_emb, padding, syn_table, syn_mask, ws);

  // 743 n-tiles of 128 cover 95000; mt fastest so the 8 blocks sharing a
  // W_rev panel run concurrently across the 8 XCDs (L3 absorbs re-reads).
  dim3 grid(8, (NCOLS + 127) / 128);
  hipLaunchKernelGGL(gemm_kernel, grid, dim3(256), 0, stream, W_rev, ws, out);
}

// Round 2
// 357.216 us; speedup vs baseline: 1.2571x; 1.2571x over previous
//
#include <hip/hip_runtime.h>
#include <stdint.h>

#define EFFECT_DIM 758
#define ADD_DIM 10
#define EMBED_DIM 768
#define NCOLS 95000
#define NSYN 8
#define NROWS 1024
#define NTILE_N 743   // ceil(95000/128)

typedef __attribute__((ext_vector_type(8))) __bf16 bf16x8;
typedef __attribute__((ext_vector_type(16))) float f32x16;
typedef __attribute__((ext_vector_type(4))) uint32_t u32x4;

// single-instruction f32 pair -> packed bf16 (RNE)
static __device__ __forceinline__ uint32_t pack2(float a, float b) {
  uint32_t r;
  asm("v_cvt_pk_bf16_f32 %0, %1, %2" : "=v"(r) : "v"(a), "v"(b));
  return r;
}

// ---------------------------------------------------------------------------
// Kernel 1: VirtualEmbedding -> bf16 A tiles at ws[0..1.5MB).
// tile(mt, ks) at (mt*12+ks)*16384 bytes, [128 rows][64 k] bf16,
// swizzled: byte(r, c2) = r*128 + (c2 ^ ((r&7)<<4)).
// ---------------------------------------------------------------------------
__global__ __launch_bounds__(256) void emb_kernel(
    const int* __restrict__ ids, const float* __restrict__ W_emb,
    const float* __restrict__ padding, const int* __restrict__ syn_table,
    const int* __restrict__ syn_mask, char* __restrict__ ws)
{
  const int l = blockIdx.x;
  const int t = threadIdx.x;
  const int id = ids[l];
  int sid[NSYN];
  int msk[NSYN];
#pragma unroll
  for (int k = 0; k < NSYN; ++k) {
    sid[k] = syn_table[id * NSYN + k];
    msk[k] = syn_mask[id * NSYN + k];
  }

  double p[9] = {0, 0, 0, 0, 0, 0, 0, 0, 0};
  for (int d = t; d < EFFECT_DIM; d += 256) {
    p[0] += (double)W_emb[(size_t)id * EFFECT_DIM + d];
#pragma unroll
    for (int k = 0; k < NSYN; ++k)
      p[k + 1] += (double)W_emb[(size_t)sid[k] * EFFECT_DIM + d];
  }

  __shared__ double s_red[9][4];
  const int w = t >> 6;
#pragma unroll
  for (int k = 0; k < 9; ++k) {
    double v = p[k];
#pragma unroll
    for (int off = 32; off > 0; off >>= 1) v += __shfl_down(v, off, 64);
    if ((t & 63) == 0) s_red[k][w] = v;
  }
  __syncthreads();

  const double isum = s_red[0][0] + s_red[0][1] + s_red[0][2] + s_red[0][3];
  float coef[NSYN];
#pragma unroll
  for (int k = 0; k < NSYN; ++k) {
    double ss = s_red[k + 1][0] + s_red[k + 1][1] + s_red[k + 1][2] + s_red[k + 1][3];
    coef[k] = msk[k] ? (float)(isum / ss) : 0.0f;
  }

  const int mt = l >> 7;
  const int r  = l & 127;
  const int sw = (r & 7) << 4;
  char* wbase = ws + (size_t)mt * (12 * 16384);

  for (int j = t; j < 384; j += 256) {
    const int d0 = 2 * j;
    float v0, v1;
    if (d0 < EFFECT_DIM) {
      const float* bp = W_emb + (size_t)id * EFFECT_DIM + d0;
      v0 = bp[0];
      v1 = bp[1];
#pragma unroll
      for (int k = 0; k < NSYN; ++k) {
        const float* sp = W_emb + (size_t)sid[k] * EFFECT_DIM + d0;
        v0 = fmaf(coef[k], sp[0], v0);
        v1 = fmaf(coef[k], sp[1], v1);
      }
    } else {
      v0 = padding[l * ADD_DIM + (d0 - EFFECT_DIM)];
      v1 = padding[l * ADD_DIM + (d0 + 1 - EFFECT_DIM)];
    }
    const int ks = j >> 5;
    const int jl = j & 31;
    *(uint32_t*)(wbase + ks * 16384 + r * 128 + ((jl * 4) ^ sw)) = pack2(v0, v1);
  }
}

// ---------------------------------------------------------------------------
// Kernel 1b: W_rev f32 [768][95000] -> bf16 [n][k] swizzled tiles.
// tile(nt, ks) at (nt*12+ks)*16384, [128 n-rows][64 k] bf16, same swizzle.
// LDS bounce so both global reads and writes stay coalesced.
// ---------------------------------------------------------------------------
__global__ __launch_bounds__(256) void conv_kernel(
    const float* __restrict__ Wrev, char* __restrict__ Bbuf)
{
  __shared__ char lds[16384];
  const int t  = threadIdx.x;
  const int nt = blockIdx.x;
  const int ks = blockIdx.y;

  const int nl = t & 127;
  const int kc_base = t >> 7;  // 0 or 1
  const int gn = nt * 128 + nl;
  const bool valid = gn < NCOLS;
  const int sw = (nl & 7) << 4;

#pragma unroll
  for (int task = 0; task < 4; ++task) {
    const int kc = kc_base + task * 2;  // 0..7 (8-k chunk)
    float v[8];
    const float* p = Wrev + (size_t)(ks * 64 + kc * 8) * NCOLS + gn;
#pragma unroll
    for (int j = 0; j < 8; ++j)
      v[j] = valid ? p[(size_t)j * NCOLS] : 0.0f;
    u32x4 u;
#pragma unroll
    for (int j = 0; j < 4; ++j)
      u[j] = pack2(v[2 * j], v[2 * j + 1]);
    *(u32x4*)(lds + nl * 128 + ((kc * 16) ^ sw)) = u;
  }
  __syncthreads();

  char* dst = Bbuf + (size_t)(nt * 12 + ks) * 16384;
#pragma unroll
  for (int i = 0; i < 4; ++i)
    *(u32x4*)(dst + t * 16 + i * 4096) = *(const u32x4*)(lds + t * 16 + i * 4096);
}

// ---------------------------------------------------------------------------
// Kernel 2 (precomputed-B path): pure-MFMA loop. Both A and B staged with
// global_load_lds (16B), fragments via swizzled ds_read_b128.
// ---------------------------------------------------------------------------
__global__ __launch_bounds__(256, 4) void gemm_pre(
    const char* __restrict__ Abuf, const char* __restrict__ Bbuf,
    float* __restrict__ out)
{
  __shared__ char lds[32768];
  const int t  = threadIdx.x;
  const int l  = t & 63;
  const int w  = t >> 6;
  const int wm = w >> 1;
  const int wn = w & 1;
  const int lr = l & 31;
  const int lh = l >> 5;
  const int mt = blockIdx.x;
  const int nt = blockIdx.y;
  const int n0 = nt * 128;

  f32x16 acc[2][2] = {};

  const char* asrc = Abuf + (size_t)mt * (12 * 16384);
  const char* bsrc = Bbuf + (size_t)nt * (12 * 16384);

  for (int ks = 0; ks < 12; ++ks) {
    {
      const char* sa = asrc + ks * 16384 + w * 1024 + l * 16;
      const char* sb = bsrc + ks * 16384 + w * 1024 + l * 16;
      char* da = lds + w * 1024;
      char* db = lds + 16384 + w * 1024;
#pragma unroll
      for (int i = 0; i < 4; ++i) {
        __builtin_amdgcn_global_load_lds(
            (const __attribute__((address_space(1))) uint32_t*)(sa + i * 4096),
            (__attribute__((address_space(3))) uint32_t*)(da + i * 4096),
            16, 0, 0);
        __builtin_amdgcn_global_load_lds(
            (const __attribute__((address_space(1))) uint32_t*)(sb + i * 4096),
            (__attribute__((address_space(3))) uint32_t*)(db + i * 4096),
            16, 0, 0);
      }
    }
    __syncthreads();

    bf16x8 af[2][4], bg[2][4];
#pragma unroll
    for (int mr = 0; mr < 2; ++mr) {
      const int rr = wm * 64 + mr * 32 + lr;
      const int swz = (rr & 7) << 4;
#pragma unroll
      for (int kk = 0; kk < 4; ++kk) {
        const int c2 = kk * 32 + lh * 16;
        af[mr][kk] = *(const bf16x8*)(lds + rr * 128 + (c2 ^ swz));
      }
    }
#pragma unroll
    for (int nr = 0; nr < 2; ++nr) {
      const int rr = wn * 64 + nr * 32 + lr;
      const int swz = (rr & 7) << 4;
#pragma unroll
      for (int kk = 0; kk < 4; ++kk) {
        const int c2 = kk * 32 + lh * 16;
        bg[nr][kk] = *(const bf16x8*)(lds + 16384 + rr * 128 + (c2 ^ swz));
      }
    }
#pragma unroll
    for (int kk = 0; kk < 4; ++kk)
#pragma unroll
      for (int mr = 0; mr < 2; ++mr)
#pragma unroll
        for (int nr = 0; nr < 2; ++nr)
          acc[mr][nr] = __builtin_amdgcn_mfma_f32_32x32x16_bf16(
              af[mr][kk], bg[nr][kk], acc[mr][nr], 0, 0, 0);
    __syncthreads();
  }

#pragma unroll
  for (int mr = 0; mr < 2; ++mr)
#pragma unroll
    for (int nr = 0; nr < 2; ++nr) {
      const int gc = n0 + wn * 64 + nr * 32 + lr;
      if (gc < NCOLS) {
#pragma unroll
        for (int reg = 0; reg < 16; ++reg) {
          const int row = (reg & 3) + 8 * (reg >> 2) + 4 * lh;
          const int gr = mt * 128 + wm * 64 + mr * 32 + row;
          out[(size_t)gr * NCOLS + gc] = acc[mr][nr][reg];
        }
      }
    }
}

// ---------------------------------------------------------------------------
// Fallback GEMM (ws too small): round-1 structure, cvt_pk pack.
// ---------------------------------------------------------------------------
__global__ __launch_bounds__(256, 2) void gemm_kernel(
    const float* __restrict__ Wrev, const char* __restrict__ Abuf,
    float* __restrict__ out)
{
  __shared__ char lds[32768];
  const int t  = threadIdx.x;
  const int l  = t & 63;
  const int w  = t >> 6;
  const int wm = w >> 1;
  const int wn = w & 1;
  const int lr = l & 31;
  const int lh = l >> 5;
  const int mt = blockIdx.x;
  const int n0 = blockIdx.y * 128;

  f32x16 acc[2][2] = {};

  const char* asrc = Abuf + (size_t)mt * (12 * 16384);
  const int nl = t & 127;
  const int kc_base = t >> 7;
  const int gn = n0 + nl;
  const int bswz = (nl & 7) << 4;

  for (int ks = 0; ks < 12; ++ks) {
    {
      const char* s = asrc + ks * 16384 + w * 1024 + l * 16;
      char* d = lds + w * 1024;
#pragma unroll
      for (int i = 0; i < 4; ++i) {
        __builtin_amdgcn_global_load_lds(
            (const __attribute__((address_space(1))) uint32_t*)(s + i * 4096),
            (__attribute__((address_space(3))) uint32_t*)(d + i * 4096),
            16, 0, 0);
      }
    }
#pragma unroll
    for (int task = 0; task < 4; ++task) {
      const int kc = kc_base + task * 2;
      float v[8];
      const float* p = Wrev + (size_t)(ks * 64 + kc * 8) * NCOLS + gn;
#pragma unroll
      for (int j = 0; j < 8; ++j)
        v[j] = (gn < NCOLS) ? p[(size_t)j * NCOLS] : 0.0f;
      u32x4 u;
#pragma unroll
      for (int j = 0; j < 4; ++j)
        u[j] = pack2(v[2 * j], v[2 * j + 1]);
      *(u32x4*)(lds + 16384 + nl * 128 + ((kc * 16) ^ bswz)) = u;
    }
    __syncthreads();

    bf16x8 af[2][4], bg[2][4];
#pragma unroll
    for (int mr = 0; mr < 2; ++mr) {
      const int rr = wm * 64 + mr * 32 + lr;
      const int swz = (rr & 7) << 4;
#pragma unroll
      for (int kk = 0; kk < 4; ++kk) {
        const int c2 = kk * 32 + lh * 16;
        af[mr][kk] = *(const bf16x8*)(lds + rr * 128 + (c2 ^ swz));
      }
    }
#pragma unroll
    for (int nr = 0; nr < 2; ++nr) {
      const int rr = wn * 64 + nr * 32 + lr;
      const int swz = (rr & 7) << 4;
#pragma unroll
      for (int kk = 0; kk < 4; ++kk) {
        const int c2 = kk * 32 + lh * 16;
        bg[nr][kk] = *(const bf16x8*)(lds + 16384 + rr * 128 + (c2 ^ swz));
      }
    }
#pragma unroll
    for (int kk = 0; kk < 4; ++kk)
#pragma unroll
      for (int mr = 0; mr < 2; ++mr)
#pragma unroll
        for (int nr = 0; nr < 2; ++nr)
          acc[mr][nr] = __builtin_amdgcn_mfma_f32_32x32x16_bf16(
              af[mr][kk], bg[nr][kk], acc[mr][nr], 0, 0, 0);
    __syncthreads();
  }

#pragma unroll
  for (int mr = 0; mr < 2; ++mr)
#pragma unroll
    for (int nr = 0; nr < 2; ++nr) {
      const int gc = n0 + wn * 64 + nr * 32 + lr;
      if (gc < NCOLS) {
#pragma unroll
        for (int reg = 0; reg < 16; ++reg) {
          const int row = (reg & 3) + 8 * (reg >> 2) + 4 * lh;
          const int gr = mt * 128 + wm * 64 + mr * 32 + row;
          out[(size_t)gr * NCOLS + gc] = acc[mr][nr][reg];
        }
      }
    }
}

extern "C" void kernel_launch(void* const* d_in, const int* in_sizes, int n_in,
                              void* d_out, int out_size, void* d_ws, size_t ws_size,
                              hipStream_t stream) {
  const int*   ids       = (const int*)d_in[0];
  const float* W_emb     = (const float*)d_in[1];
  const float* W_rev     = (const float*)d_in[2];
  const float* padding   = (const float*)d_in[3];
  const int*   syn_table = (const int*)d_in[4];
  const int*   syn_mask  = (const int*)d_in[5];
  float* out = (float*)d_out;
  char*  ws  = (char*)d_ws;

  const size_t A_BYTES = (size_t)8 * 12 * 16384;            // 1.5 MB
  const size_t B_BYTES = (size_t)NTILE_N * 12 * 16384;      // ~146 MB

  hipLaunchKernelGGL(emb_kernel, dim3(NROWS), dim3(256), 0, stream,
                     ids, W_emb, padding, syn_table, syn_mask, ws);

  if (ws_size >= A_BYTES + B_BYTES) {
    char* Bbuf = ws + A_BYTES;
    hipLaunchKernelGGL(conv_kernel, dim3(NTILE_N, 12), dim3(256), 0, stream,
                       W_rev, Bbuf);
    hipLaunchKernelGGL(gemm_pre, dim3(8, NTILE_N), dim3(256), 0, stream,
                       ws, Bbuf, out);
  } else {
    hipLaunchKernelGGL(gemm_kernel, dim3(8, NTILE_N), dim3(256), 0, stream,
                       W_rev, ws, out);
  }
}